// Round 3
// baseline (215.861 us; speedup 1.0000x reference)
//
#include <hip/hip_runtime.h>
#include <hip/hip_bf16.h>

#define IN_F   1024
#define OUT_F  1024
#define GRID_N 8
#define TOKENS 8192
#define KTOT   9216
#define KHALF  4608
#define NTILE  72          // KHALF / 64

typedef __attribute__((ext_vector_type(8))) short  bf16x8;
typedef __attribute__((ext_vector_type(4))) float  f32x4;

struct TrueT  { static constexpr bool value = true;  };
struct FalseT { static constexpr bool value = false; };

__device__ __forceinline__ unsigned int f2bf(float f) {
    union { float f; unsigned int u; } v; v.f = f;
    unsigned int r = v.u + 0x7fffu + ((v.u >> 16) & 1u);
    return r >> 16;
}

// One thread per (t, i): silu(x) -> A[t][i]; 8 RBF basis -> A[t][1024+i*8..] (16B store)
__global__ __launch_bounds__(256)
void prep_a_kernel(const float* __restrict__ x, const float* __restrict__ grid,
                   unsigned short* __restrict__ A)
{
    int idx = blockIdx.x * blockDim.x + threadIdx.x;
    int t = idx >> 10;
    int i = idx & 1023;
    float xv = x[idx];
    float sil = xv / (1.0f + __expf(-xv));
    A[(size_t)t * KTOT + i] = (unsigned short)f2bf(sil);

    const float invd = 1.0f / (2.0f / 7.0f + 1e-5f);
    unsigned int h[8];
    #pragma unroll
    for (int g = 0; g < 8; ++g) {
        float d = (xv - grid[g]) * invd;
        h[g] = f2bf(__expf(-d * d));
    }
    uint4 pk;
    pk.x = h[0] | (h[1] << 16);
    pk.y = h[2] | (h[3] << 16);
    pk.z = h[4] | (h[5] << 16);
    pk.w = h[6] | (h[7] << 16);
    *reinterpret_cast<uint4*>(&A[(size_t)t * KTOT + IN_F + (size_t)i * 8]) = pk;
}

// Repack W [O,1024] and spline [O,1024,8] into bf16 B [O, 9216].
__global__ __launch_bounds__(256)
void prep_b_kernel(const float* __restrict__ W, const float* __restrict__ spl,
                   unsigned short* __restrict__ B)
{
    int idx = blockIdx.x * blockDim.x + threadIdx.x;
    int o  = idx / (KTOT / 8);
    int c8 = idx - o * (KTOT / 8);
    const float* src = (c8 < IN_F / 8)
        ? (W   + (size_t)o * IN_F            + (size_t)c8 * 8)
        : (spl + (size_t)o * (IN_F * GRID_N) + (size_t)(c8 - IN_F / 8) * 8);
    const float4* s4 = reinterpret_cast<const float4*>(src);
    float4 lo = s4[0], hi = s4[1];
    uint4 pk;
    pk.x = f2bf(lo.x) | (f2bf(lo.y) << 16);
    pk.y = f2bf(lo.z) | (f2bf(lo.w) << 16);
    pk.z = f2bf(hi.x) | (f2bf(hi.y) << 16);
    pk.w = f2bf(hi.z) | (f2bf(hi.w) << 16);
    *reinterpret_cast<uint4*>(&B[(size_t)o * KTOT + (size_t)c8 * 8]) = pk;
}

// ---------------------------------------------------------------------------
// 256x256 tile, BK=64, 8 waves (2M x 4N), split-K=2, 4 phases/K-tile.
// Counted-vmcnt pipeline (T4): all 8 next-tile gload_lds issued at phase 1;
// waits vmcnt(8)@p1 (guards current tile, 4-phase cover) and vmcnt(4)@p4
// (guards next tile's phase-1 halves, 3-phase cover). Never vmcnt(0) in loop.
// Wave->fragment map interleaved so each phase reads contiguous 128-row halves:
//   A row(mi) = wr*64 + (mi&3)*16 + (mi>>2)*128   (mh = mi>>2 -> A-lo/A-hi)
//   B col(ni) = wc*32 + (ni&1)*16 + (ni>>1)*128   (nh = ni>>1 -> B-lo/B-hi)
// ---------------------------------------------------------------------------
#define GLOAD(src, dst) __builtin_amdgcn_global_load_lds( \
    (const __attribute__((address_space(1))) void*)(src),  \
    (__attribute__((address_space(3))) void*)(dst), 16, 0, 0)
#define SBAR()  __builtin_amdgcn_s_barrier()
#define SCH0()  __builtin_amdgcn_sched_barrier(0)
#define LGKM0() asm volatile("s_waitcnt lgkmcnt(0)" ::: "memory")
#define VMCNT_(n) asm volatile("s_waitcnt vmcnt(" #n ")" ::: "memory")

__global__ __launch_bounds__(512, 2)
void gemm_kan2(const unsigned short* __restrict__ A,
               const unsigned short* __restrict__ B,
               float* __restrict__ P, int rows)
{
    __shared__ char lds[131072];   // 2 bufs x (A 32KB + B 32KB)

    const int bid  = blockIdx.x;
    const int sk   = bid & 1;            // XCD = bid&7 owns one (bn,sk) pair:
    const int bn   = (bid >> 1) & 3;     // its 2.36 MB B-panel stays in its L2
    const int bm   = bid >> 3;
    const int tid  = threadIdx.x;
    const int wave = tid >> 6, lane = tid & 63;
    const int wr   = wave >> 2, wc = wave & 3;
    const int fr   = lane & 15, kg = lane >> 4;
    const int sw   = fr & 7;
    const int koff[2] = { (kg ^ sw) * 16, ((4 | kg) ^ sw) * 16 };
    const int k0 = sk * KHALF;

    // staging: thread covers row (tid>>3), 16B chunk (tid&7), inverse-swizzled k
    const int trow = tid >> 3;
    const int ksrc = ((tid & 7) ^ (trow & 7)) * 8;
    const unsigned short* gA = A + (size_t)(bm * 256 + trow) * KTOT + k0 + ksrc;
    const unsigned short* gB = B + (size_t)(bn * 256 + trow) * KTOT + k0 + ksrc;
    const size_t R64 = (size_t)64 * KTOT;

    f32x4 acc[8][4];
    const f32x4 zero = {0.f, 0.f, 0.f, 0.f};
    #pragma unroll
    for (int m = 0; m < 8; ++m)
        #pragma unroll
        for (int n = 0; n < 4; ++n) acc[m][n] = zero;

    // prologue: stage tile 0 -> buf0 (order: A-lo, B-lo, B-hi, A-hi)
    {
        char* d = lds + tid * 16;
        GLOAD(gA,           d);            GLOAD(gA + R64,     d + 8192);
        GLOAD(gB,           d + 32768);    GLOAD(gB + R64,     d + 40960);
        GLOAD(gB + 2 * R64, d + 49152);    GLOAD(gB + 3 * R64, d + 57344);
        GLOAD(gA + 2 * R64, d + 16384);    GLOAD(gA + 3 * R64, d + 24576);
        gA += 64; gB += 64;
    }
    VMCNT_(4); SBAR(); SCH0();   // A-lo(0), B-lo(0) resident for phase 1

    const int aOff = (wr * 64 + fr) * 128;           // + (mi&3)*2048 + (mi>>2)*16384
    const int bOff = 32768 + (wc * 32 + fr) * 128;   // + (ni&1)*2048 + (ni>>1)*16384

    bf16x8 af[4][2], bf[2][2];
    int u = 0;

    auto tile = [&](auto stC) {
        constexpr bool ST = decltype(stC)::value;
        char* bufc = lds + (u & 1) * 65536;

        // ---- phase 1 (mh=0, nh=0): read A-lo + B-lo; stage ALL next-tile ----
        #pragma unroll
        for (int mi = 0; mi < 4; ++mi)
            #pragma unroll
            for (int ks = 0; ks < 2; ++ks)
                af[mi][ks] = *(const bf16x8*)(bufc + aOff + mi * 2048 + koff[ks]);
        #pragma unroll
        for (int ni = 0; ni < 2; ++ni)
            #pragma unroll
            for (int ks = 0; ks < 2; ++ks)
                bf[ni][ks] = *(const bf16x8*)(bufc + bOff + ni * 2048 + koff[ks]);
        if constexpr (ST) {
            char* d = lds + ((u & 1) ^ 1) * 65536 + tid * 16;
            GLOAD(gA,           d);            GLOAD(gA + R64,     d + 8192);
            GLOAD(gB,           d + 32768);    GLOAD(gB + R64,     d + 40960);
            GLOAD(gB + 2 * R64, d + 49152);    GLOAD(gB + 3 * R64, d + 57344);
            GLOAD(gA + 2 * R64, d + 16384);    GLOAD(gA + 3 * R64, d + 24576);
            VMCNT_(8);     // all current-tile units resident (issued 4 phases ago)
        } else {
            VMCNT_(0);     // last tile: drain once
        }
        SBAR(); SCH0(); LGKM0(); SCH0();
        __builtin_amdgcn_s_setprio(1);
        #pragma unroll
        for (int mi = 0; mi < 4; ++mi)
            #pragma unroll
            for (int ni = 0; ni < 2; ++ni)
                #pragma unroll
                for (int ks = 0; ks < 2; ++ks)
                    acc[mi][ni] = __builtin_amdgcn_mfma_f32_16x16x32_bf16(
                        af[mi][ks], bf[ni][ks], acc[mi][ni], 0, 0, 0);
        __builtin_amdgcn_s_setprio(0);
        SBAR(); SCH0();

        // ---- phase 2 (mh=0, nh=1): read B-hi ----
        #pragma unroll
        for (int ni = 0; ni < 2; ++ni)
            #pragma unroll
            for (int ks = 0; ks < 2; ++ks)
                bf[ni][ks] = *(const bf16x8*)(bufc + bOff + 16384 + ni * 2048 + koff[ks]);
        SBAR(); SCH0(); LGKM0(); SCH0();
        __builtin_amdgcn_s_setprio(1);
        #pragma unroll
        for (int mi = 0; mi < 4; ++mi)
            #pragma unroll
            for (int ni = 0; ni < 2; ++ni)
                #pragma unroll
                for (int ks = 0; ks < 2; ++ks)
                    acc[mi][2 + ni] = __builtin_amdgcn_mfma_f32_16x16x32_bf16(
                        af[mi][ks], bf[ni][ks], acc[mi][2 + ni], 0, 0, 0);
        __builtin_amdgcn_s_setprio(0);
        SBAR(); SCH0();

        // ---- phase 3 (mh=1, nh=0): read A-hi + B-lo ----
        #pragma unroll
        for (int mi = 0; mi < 4; ++mi)
            #pragma unroll
            for (int ks = 0; ks < 2; ++ks)
                af[mi][ks] = *(const bf16x8*)(bufc + aOff + 16384 + mi * 2048 + koff[ks]);
        #pragma unroll
        for (int ni = 0; ni < 2; ++ni)
            #pragma unroll
            for (int ks = 0; ks < 2; ++ks)
                bf[ni][ks] = *(const bf16x8*)(bufc + bOff + ni * 2048 + koff[ks]);
        SBAR(); SCH0(); LGKM0(); SCH0();
        __builtin_amdgcn_s_setprio(1);
        #pragma unroll
        for (int mi = 0; mi < 4; ++mi)
            #pragma unroll
            for (int ni = 0; ni < 2; ++ni)
                #pragma unroll
                for (int ks = 0; ks < 2; ++ks)
                    acc[4 + mi][ni] = __builtin_amdgcn_mfma_f32_16x16x32_bf16(
                        af[mi][ks], bf[ni][ks], acc[4 + mi][ni], 0, 0, 0);
        __builtin_amdgcn_s_setprio(0);
        SBAR(); SCH0();

        // ---- phase 4 (mh=1, nh=1): read B-hi; counted wait for next phase 1 ----
        #pragma unroll
        for (int ni = 0; ni < 2; ++ni)
            #pragma unroll
            for (int ks = 0; ks < 2; ++ks)
                bf[ni][ks] = *(const bf16x8*)(bufc + bOff + 16384 + ni * 2048 + koff[ks]);
        if constexpr (ST) {
            VMCNT_(4);     // next tile's A-lo/B-lo resident (B-hi/A-hi may fly)
        }
        SBAR(); SCH0(); LGKM0(); SCH0();
        __builtin_amdgcn_s_setprio(1);
        #pragma unroll
        for (int mi = 0; mi < 4; ++mi)
            #pragma unroll
            for (int ni = 0; ni < 2; ++ni)
                #pragma unroll
                for (int ks = 0; ks < 2; ++ks)
                    acc[4 + mi][2 + ni] = __builtin_amdgcn_mfma_f32_16x16x32_bf16(
                        af[mi][ks], bf[ni][ks], acc[4 + mi][2 + ni], 0, 0, 0);
        __builtin_amdgcn_s_setprio(0);
        SBAR(); SCH0();

        if constexpr (ST) { gA += 64; gB += 64; }
    };

    for (u = 0; u < NTILE - 1; ++u) tile(TrueT{});
    tile(FalseT{});

    // epilogue: write f32 partials (interleaved-quadrant mapping)
    float* Pp = P + (size_t)sk * rows * OUT_F;
    const size_t orow0 = (size_t)bm * 256 + (size_t)wr * 64;
    const int    ocol0 = bn * 256 + wc * 32;
    #pragma unroll
    for (int n = 0; n < 4; ++n) {
        const int col = ocol0 + (n & 1) * 16 + (n >> 1) * 128 + fr;
        #pragma unroll
        for (int m = 0; m < 8; ++m) {
            const size_t r0 = orow0 + (m & 3) * 16 + (m >> 2) * 128 + kg * 4;
            #pragma unroll
            for (int j = 0; j < 4; ++j)
                Pp[(r0 + j) * OUT_F + col] = acc[m][n][j];
        }
    }
}

// out = P0 + P1 + bias
__global__ __launch_bounds__(256)
void reduce_kan(const float* __restrict__ P, const float* __restrict__ bias,
                float* __restrict__ out, int n4, int skStride4)
{
    const float4* p0 = (const float4*)P;
    const float4* p1 = p0 + skStride4;
    const float4* bv = (const float4*)bias;
    float4* o = (float4*)out;
    for (int i = blockIdx.x * blockDim.x + threadIdx.x; i < n4;
         i += gridDim.x * blockDim.x) {
        float4 a = p0[i], b = p1[i], c = bv[i & 255];
        float4 r;
        r.x = a.x + b.x + c.x;  r.y = a.y + b.y + c.y;
        r.z = a.z + b.z + c.z;  r.w = a.w + b.w + c.w;
        o[i] = r;
    }
}

extern "C" void kernel_launch(void* const* d_in, const int* in_sizes, int n_in,
                              void* d_out, int out_size, void* d_ws, size_t ws_size,
                              hipStream_t stream)
{
    const float* x    = (const float*)d_in[0];
    const float* W    = (const float*)d_in[1];
    const float* bias = (const float*)d_in[2];
    const float* spl  = (const float*)d_in[3];
    const float* grid = (const float*)d_in[4];
    float* out = (float*)d_out;

    unsigned short* Bw = (unsigned short*)d_ws;               // 18.9 MB
    unsigned short* Aw = Bw + (size_t)OUT_F * KTOT;

    // per-row ws: A bf16 (18432 B) + 2x f32 partial (8192 B)
    const size_t bBytes = (size_t)OUT_F * KTOT * 2;
    size_t avail = ws_size > bBytes ? ws_size - bBytes : 0;
    long maxRows = (long)(avail / 26624);
    int chunk = (maxRows >= TOKENS) ? TOKENS : (int)((maxRows / 256) * 256);
    if (chunk < 256) chunk = 256;
    float* Pp = (float*)(Aw + (size_t)chunk * KTOT);

    prep_b_kernel<<<(OUT_F * (KTOT / 8)) / 256, 256, 0, stream>>>(W, spl, Bw);

    for (int t0 = 0; t0 < TOKENS; t0 += chunk) {
        int rows = (TOKENS - t0 < chunk) ? (TOKENS - t0) : chunk;
        prep_a_kernel<<<(rows * IN_F) / 256, 256, 0, stream>>>(
            x + (size_t)t0 * IN_F, grid, Aw);
        gemm_kan2<<<(rows >> 8) * 8, 512, 0, stream>>>(Aw, Bw, Pp, rows);
        int n4 = rows * 256;
        int rblocks = (n4 + 255) / 256; if (rblocks > 2048) rblocks = 2048;
        reduce_kan<<<rblocks, 256, 0, stream>>>(
            Pp, bias, out + (size_t)t0 * OUT_F, n4, n4);
    }
}

// Round 4
// 202.420 us; speedup vs baseline: 1.0664x; 1.0664x over previous
//
#include <hip/hip_runtime.h>
#include <hip/hip_bf16.h>

#define IN_F   1024
#define OUT_F  1024
#define GRID_N 8
#define TOKENS 8192
#define KTOT   9216
#define KHALF  4608
#define NTILE  72          // KHALF / 64

typedef __attribute__((ext_vector_type(8))) short  bf16x8;
typedef __attribute__((ext_vector_type(4))) float  f32x4;

template<int M> struct ModeT { static constexpr int value = M; };

__device__ __forceinline__ unsigned int f2bf(float f) {
    union { float f; unsigned int u; } v; v.f = f;
    unsigned int r = v.u + 0x7fffu + ((v.u >> 16) & 1u);
    return r >> 16;
}

// One thread per (t, i): silu(x) -> A[t][i]; 8 RBF basis -> A[t][1024+i*8..] (16B store)
__global__ __launch_bounds__(256)
void prep_a_kernel(const float* __restrict__ x, const float* __restrict__ grid,
                   unsigned short* __restrict__ A)
{
    int idx = blockIdx.x * blockDim.x + threadIdx.x;
    int t = idx >> 10;
    int i = idx & 1023;
    float xv = x[idx];
    float sil = xv / (1.0f + __expf(-xv));
    A[(size_t)t * KTOT + i] = (unsigned short)f2bf(sil);

    const float invd = 1.0f / (2.0f / 7.0f + 1e-5f);
    unsigned int h[8];
    #pragma unroll
    for (int g = 0; g < 8; ++g) {
        float d = (xv - grid[g]) * invd;
        h[g] = f2bf(__expf(-d * d));
    }
    uint4 pk;
    pk.x = h[0] | (h[1] << 16);
    pk.y = h[2] | (h[3] << 16);
    pk.z = h[4] | (h[5] << 16);
    pk.w = h[6] | (h[7] << 16);
    *reinterpret_cast<uint4*>(&A[(size_t)t * KTOT + IN_F + (size_t)i * 8]) = pk;
}

// Repack W [O,1024] and spline [O,1024,8] into bf16 B [O, 9216].
__global__ __launch_bounds__(256)
void prep_b_kernel(const float* __restrict__ W, const float* __restrict__ spl,
                   unsigned short* __restrict__ B)
{
    int idx = blockIdx.x * blockDim.x + threadIdx.x;
    int o  = idx / (KTOT / 8);
    int c8 = idx - o * (KTOT / 8);
    const float* src = (c8 < IN_F / 8)
        ? (W   + (size_t)o * IN_F            + (size_t)c8 * 8)
        : (spl + (size_t)o * (IN_F * GRID_N) + (size_t)(c8 - IN_F / 8) * 8);
    const float4* s4 = reinterpret_cast<const float4*>(src);
    float4 lo = s4[0], hi = s4[1];
    uint4 pk;
    pk.x = f2bf(lo.x) | (f2bf(lo.y) << 16);
    pk.y = f2bf(lo.z) | (f2bf(lo.w) << 16);
    pk.z = f2bf(hi.x) | (f2bf(hi.y) << 16);
    pk.w = f2bf(hi.z) | (f2bf(hi.w) << 16);
    *reinterpret_cast<uint4*>(&B[(size_t)o * KTOT + (size_t)c8 * 8]) = pk;
}

// ---------------------------------------------------------------------------
// 256x256 tile, BK=64, 8 waves (2M x 4N), split-K=2, 4 phases/K-tile.
// m201-style staggered-unit pipeline: tile u+2's units overwrite the CURRENT
// buffer as tile u consumes them (stage rhythm 0/4/2/2 gloads per phase),
// giving every unit 7 phases (~1000 cy) of latency cover. Counted waits
// derived from issue order: vmcnt 10/12/-/12 steady, 10/8/-/4 and 2/0/-/-
// on the two tail tiles. Register-cached B (both halves) + A half reuse so
// each unit's LDS copy dies right after its read phase.
//   A row(mi) = wr*64 + (mi&3)*16 + (mi>>2)*128
//   B col(ni) = wc*32 + (ni&1)*16 + (ni>>1)*128
// Quadrants: p1 (mh0,nh0)  p2 (mh0,nh1)  p3 (mh1,nh1)  p4 (mh1,nh0)
// ---------------------------------------------------------------------------
#define GLOAD(src, dst) __builtin_amdgcn_global_load_lds( \
    (const __attribute__((address_space(1))) void*)(src),  \
    (__attribute__((address_space(3))) void*)(dst), 16, 0, 0)
#define SBAR()  __builtin_amdgcn_s_barrier()
#define SCH0()  __builtin_amdgcn_sched_barrier(0)
#define LGKM0() asm volatile("s_waitcnt lgkmcnt(0)" ::: "memory")
#define VMCNT_(n) asm volatile("s_waitcnt vmcnt(" #n ")" ::: "memory")

__global__ __launch_bounds__(512, 2)
void gemm_kan2(const unsigned short* __restrict__ A,
               const unsigned short* __restrict__ B,
               float* __restrict__ P, int rows)
{
    __shared__ char lds[131072];   // 2 bufs x (A 32KB + B 32KB)

    const int bid  = blockIdx.x;
    const int sk   = bid & 1;            // XCD = bid&7 owns one (bn,sk) pair:
    const int bn   = (bid >> 1) & 3;     // its 2.36 MB B-panel stays in its L2
    const int bm   = bid >> 3;
    const int tid  = threadIdx.x;
    const int wave = tid >> 6, lane = tid & 63;
    const int wr   = wave >> 2, wc = wave & 3;
    const int fr   = lane & 15, kg = lane >> 4;
    const int sw   = fr & 7;
    const int koff[2] = { (kg ^ sw) * 16, ((4 | kg) ^ sw) * 16 };
    const int k0 = sk * KHALF;

    // staging: thread covers row (tid>>3), 16B chunk (tid&7), inverse-swizzled k
    const int trow = tid >> 3;
    const int ksrc = ((tid & 7) ^ (trow & 7)) * 8;
    const unsigned short* gA = A + (size_t)(bm * 256 + trow) * KTOT + k0 + ksrc;
    const unsigned short* gB = B + (size_t)(bn * 256 + trow) * KTOT + k0 + ksrc;
    const size_t R64 = (size_t)64 * KTOT;

    f32x4 acc[8][4];
    const f32x4 zero = {0.f, 0.f, 0.f, 0.f};
    #pragma unroll
    for (int m = 0; m < 8; ++m)
        #pragma unroll
        for (int n = 0; n < 4; ++n) acc[m][n] = zero;

    // prologue: stage tile0 -> buf0, tile1 -> buf1
    // unit order per tile: A-lo, B-lo, B-hi, A-hi (matches steady issue order)
    {
        char* d = lds + tid * 16;
        GLOAD(gA,           d);            GLOAD(gA + R64,     d + 8192);
        GLOAD(gB,           d + 32768);    GLOAD(gB + R64,     d + 40960);
        GLOAD(gB + 2 * R64, d + 49152);    GLOAD(gB + 3 * R64, d + 57344);
        GLOAD(gA + 2 * R64, d + 16384);    GLOAD(gA + 3 * R64, d + 24576);
        gA += 64; gB += 64;
        d += 65536;
        GLOAD(gA,           d);            GLOAD(gA + R64,     d + 8192);
        GLOAD(gB,           d + 32768);    GLOAD(gB + R64,     d + 40960);
        GLOAD(gB + 2 * R64, d + 49152);    GLOAD(gB + 3 * R64, d + 57344);
        GLOAD(gA + 2 * R64, d + 16384);    GLOAD(gA + 3 * R64, d + 24576);
        gA += 64; gB += 64;
    }
    VMCNT_(12); SBAR(); SCH0();   // tile0 A-lo,B-lo resident for phase 1

    const int aOff = (wr * 64 + fr) * 128;           // + (mi&3)*2048 + (mi>>2)*16384
    const int bOff = 32768 + (wc * 32 + fr) * 128;   // + (ni&1)*2048 + (ni>>1)*16384

    bf16x8 af[4][2], bfLo[2][2], bfHi[2][2];
    int u = 0;

    // MODE: 0 = steady (stages tile u+2), 1 = tail1 (u = NTILE-2), 2 = tail2
    auto tile = [&](auto mC) {
        constexpr int MODE = decltype(mC)::value;
        char* bufc = lds + (u & 1) * 65536;
        char* d    = bufc + tid * 16;

        // ---- phase 1 (mh0,nh0): read A-lo frags + B-lo frags; no staging ----
        #pragma unroll
        for (int mi = 0; mi < 4; ++mi)
            #pragma unroll
            for (int ks = 0; ks < 2; ++ks)
                af[mi][ks] = *(const bf16x8*)(bufc + aOff + mi * 2048 + koff[ks]);
        #pragma unroll
        for (int ni = 0; ni < 2; ++ni)
            #pragma unroll
            for (int ks = 0; ks < 2; ++ks)
                bfLo[ni][ks] = *(const bf16x8*)(bufc + bOff + ni * 2048 + koff[ks]);
        if constexpr (MODE == 0) { VMCNT_(10); }       // B-hi(u) resident for p2
        else if constexpr (MODE == 1) { VMCNT_(10); }
        else { VMCNT_(2); }
        SBAR(); SCH0(); LGKM0(); SCH0();
        __builtin_amdgcn_s_setprio(1);
        #pragma unroll
        for (int mi = 0; mi < 4; ++mi)
            #pragma unroll
            for (int ni = 0; ni < 2; ++ni)
                #pragma unroll
                for (int ks = 0; ks < 2; ++ks)
                    acc[mi][ni] = __builtin_amdgcn_mfma_f32_16x16x32_bf16(
                        af[mi][ks], bfLo[ni][ks], acc[mi][ni], 0, 0, 0);
        __builtin_amdgcn_s_setprio(0);
        SBAR(); SCH0();

        // ---- phase 2 (mh0,nh1): read B-hi; stage A-lo,B-lo of tile u+2 ----
        #pragma unroll
        for (int ni = 0; ni < 2; ++ni)
            #pragma unroll
            for (int ks = 0; ks < 2; ++ks)
                bfHi[ni][ks] = *(const bf16x8*)(bufc + bOff + 16384 + ni * 2048 + koff[ks]);
        if constexpr (MODE == 0) {
            GLOAD(gA,       d);            GLOAD(gA + R64, d + 8192);
            GLOAD(gB,       d + 32768);    GLOAD(gB + R64, d + 40960);
            VMCNT_(12);                    // A-hi(u) resident for p3
        } else if constexpr (MODE == 1) { VMCNT_(8); }
        else { VMCNT_(0); }
        SBAR(); SCH0(); LGKM0(); SCH0();
        __builtin_amdgcn_s_setprio(1);
        #pragma unroll
        for (int mi = 0; mi < 4; ++mi)
            #pragma unroll
            for (int ni = 0; ni < 2; ++ni)
                #pragma unroll
                for (int ks = 0; ks < 2; ++ks)
                    acc[mi][2 + ni] = __builtin_amdgcn_mfma_f32_16x16x32_bf16(
                        af[mi][ks], bfHi[ni][ks], acc[mi][2 + ni], 0, 0, 0);
        __builtin_amdgcn_s_setprio(0);
        SBAR(); SCH0();

        // ---- phase 3 (mh1,nh1): read A-hi (af reuse); stage B-hi of u+2 ----
        #pragma unroll
        for (int mi = 0; mi < 4; ++mi)
            #pragma unroll
            for (int ks = 0; ks < 2; ++ks)
                af[mi][ks] = *(const bf16x8*)(bufc + aOff + 16384 + mi * 2048 + koff[ks]);
        if constexpr (MODE == 0) {
            GLOAD(gB + 2 * R64, d + 49152);  GLOAD(gB + 3 * R64, d + 57344);
        }
        SBAR(); SCH0(); LGKM0(); SCH0();   // no vmcnt: p4 reads nothing
        __builtin_amdgcn_s_setprio(1);
        #pragma unroll
        for (int mi = 0; mi < 4; ++mi)
            #pragma unroll
            for (int ni = 0; ni < 2; ++ni)
                #pragma unroll
                for (int ks = 0; ks < 2; ++ks)
                    acc[4 + mi][2 + ni] = __builtin_amdgcn_mfma_f32_16x16x32_bf16(
                        af[mi][ks], bfHi[ni][ks], acc[4 + mi][2 + ni], 0, 0, 0);
        __builtin_amdgcn_s_setprio(0);
        SBAR(); SCH0();

        // ---- phase 4 (mh1,nh0): no reads (bfLo cached); stage A-hi of u+2 ----
        if constexpr (MODE == 0) {
            GLOAD(gA + 2 * R64, d + 16384);  GLOAD(gA + 3 * R64, d + 24576);
            VMCNT_(12);                    // A-lo,B-lo(u+1) resident for next p1
        } else if constexpr (MODE == 1) { VMCNT_(4); }
        SBAR(); SCH0();
        __builtin_amdgcn_s_setprio(1);
        #pragma unroll
        for (int mi = 0; mi < 4; ++mi)
            #pragma unroll
            for (int ni = 0; ni < 2; ++ni)
                #pragma unroll
                for (int ks = 0; ks < 2; ++ks)
                    acc[4 + mi][ni] = __builtin_amdgcn_mfma_f32_16x16x32_bf16(
                        af[mi][ks], bfLo[ni][ks], acc[4 + mi][ni], 0, 0, 0);
        __builtin_amdgcn_s_setprio(0);
        SBAR(); SCH0();

        if constexpr (MODE == 0) { gA += 64; gB += 64; }
    };

    for (u = 0; u < NTILE - 2; ++u) tile(ModeT<0>{});
    tile(ModeT<1>{});          // u == NTILE-2
    ++u;
    tile(ModeT<2>{});          // u == NTILE-1

    // epilogue: write f32 partials (interleaved-quadrant mapping)
    float* Pp = P + (size_t)sk * rows * OUT_F;
    const size_t orow0 = (size_t)bm * 256 + (size_t)wr * 64;
    const int    ocol0 = bn * 256 + wc * 32;
    #pragma unroll
    for (int n = 0; n < 4; ++n) {
        const int col = ocol0 + (n & 1) * 16 + (n >> 1) * 128 + fr;
        #pragma unroll
        for (int m = 0; m < 8; ++m) {
            const size_t r0 = orow0 + (m & 3) * 16 + (m >> 2) * 128 + kg * 4;
            #pragma unroll
            for (int j = 0; j < 4; ++j)
                Pp[(r0 + j) * OUT_F + col] = acc[m][n][j];
        }
    }
}

// out = P0 + P1 + bias
__global__ __launch_bounds__(256)
void reduce_kan(const float* __restrict__ P, const float* __restrict__ bias,
                float* __restrict__ out, int n4, int skStride4)
{
    const float4* p0 = (const float4*)P;
    const float4* p1 = p0 + skStride4;
    const float4* bv = (const float4*)bias;
    float4* o = (float4*)out;
    for (int i = blockIdx.x * blockDim.x + threadIdx.x; i < n4;
         i += gridDim.x * blockDim.x) {
        float4 a = p0[i], b = p1[i], c = bv[i & 255];
        float4 r;
        r.x = a.x + b.x + c.x;  r.y = a.y + b.y + c.y;
        r.z = a.z + b.z + c.z;  r.w = a.w + b.w + c.w;
        o[i] = r;
    }
}

extern "C" void kernel_launch(void* const* d_in, const int* in_sizes, int n_in,
                              void* d_out, int out_size, void* d_ws, size_t ws_size,
                              hipStream_t stream)
{
    const float* x    = (const float*)d_in[0];
    const float* W    = (const float*)d_in[1];
    const float* bias = (const float*)d_in[2];
    const float* spl  = (const float*)d_in[3];
    const float* grid = (const float*)d_in[4];
    float* out = (float*)d_out;

    unsigned short* Bw = (unsigned short*)d_ws;               // 18.9 MB
    unsigned short* Aw = Bw + (size_t)OUT_F * KTOT;

    // per-row ws: A bf16 (18432 B) + 2x f32 partial (8192 B)
    const size_t bBytes = (size_t)OUT_F * KTOT * 2;
    size_t avail = ws_size > bBytes ? ws_size - bBytes : 0;
    long maxRows = (long)(avail / 26624);
    int chunk = (maxRows >= TOKENS) ? TOKENS : (int)((maxRows / 256) * 256);
    if (chunk < 256) chunk = 256;
    float* Pp = (float*)(Aw + (size_t)chunk * KTOT);

    prep_b_kernel<<<(OUT_F * (KTOT / 8)) / 256, 256, 0, stream>>>(W, spl, Bw);

    for (int t0 = 0; t0 < TOKENS; t0 += chunk) {
        int rows = (TOKENS - t0 < chunk) ? (TOKENS - t0) : chunk;
        prep_a_kernel<<<(rows * IN_F) / 256, 256, 0, stream>>>(
            x + (size_t)t0 * IN_F, grid, Aw);
        gemm_kan2<<<(rows >> 8) * 8, 512, 0, stream>>>(Aw, Bw, Pp, rows);
        int n4 = rows * 256;
        int rblocks = (n4 + 255) / 256; if (rblocks > 2048) rblocks = 2048;
        reduce_kan<<<rblocks, 256, 0, stream>>>(
            Pp, bias, out + (size_t)t0 * OUT_F, n4, n4);
    }
}